// Round 1
// 102.787 us; speedup vs baseline: 1.0231x; 1.0231x over previous
//
#include <hip/hip_runtime.h>

// Varlen non-causal attention, qkv-packed (T,3,H,D) fp32 in/out.
// 2-kernel pipeline:
//  1) prep:   fp32 K,V -> bf16 Kb[h][t][d], Vtb[h][d][t]  (Q converted in-kernel)
//  2) main:   bf16 MFMA flash attention, NSPLIT=1, double-buffered K/V staging
//             via global_load_lds(16B) into XOR-swizzled LDS; schedule per chunk:
//             {STAGE(next buf) ; compute(cur buf) ; vmcnt(0)+barrier}  (1 barrier/chunk,
//             DMA latency hidden under MFMA+softmax). Defer-max (exact, THR=0) +
//             s_setprio around MFMA clusters.

#define HEADS 8
#define DH 64
#define TQ 64
#define TK 64
#define PSTR 72
#define NEG_BIG -1e30f
#define L2E 1.44269504088896340736f

using f32x4 = __attribute__((ext_vector_type(4))) float;
using s16x8 = __attribute__((ext_vector_type(8))) short;

__device__ inline unsigned short bf16b(float x) {
    union { float f; unsigned u; } c; c.f = x;
    unsigned r = c.u + 0x7fffu + ((c.u >> 16) & 1u);   // RNE
    return (unsigned short)(r >> 16);
}

#if __has_builtin(__builtin_amdgcn_cvt_pk_bf16_f32)
__device__ inline unsigned pk2(float a, float b) {
    auto v = __builtin_amdgcn_cvt_pk_bf16_f32(a, b);
    unsigned u; __builtin_memcpy(&u, &v, 4); return u;
}
#else
__device__ inline unsigned pk2(float a, float b) {
    return (unsigned)bf16b(a) | ((unsigned)bf16b(b) << 16);
}
#endif

// ---------------- pre-pass: convert + re-layout K and V only ----------------
__global__ __launch_bounds__(256)
void prep_kernel(const float* __restrict__ qkv, unsigned short* __restrict__ Kb,
                 unsigned short* __restrict__ Vtb, int T) {
    __shared__ unsigned short Lt[64][PSTR];
    const int m = 1 + blockIdx.z, h = blockIdx.y, t0 = blockIdx.x * 64;
    const int tid = threadIdx.x, d8 = tid & 7, tr = tid >> 3;   // tr 0..31

    #pragma unroll
    for (int i = 0; i < 2; ++i) {
        int t = t0 + i * 32 + tr;
        int tc = t < T ? t : T - 1;
        const float* src = qkv + ((size_t)tc * 3 + m) * (HEADS * DH) + h * DH + d8 * 8;
        float4 a = *(const float4*)src;
        float4 b = *(const float4*)(src + 4);
        unsigned p0 = pk2(a.x, a.y), p1 = pk2(a.z, a.w);
        unsigned p2 = pk2(b.x, b.y), p3 = pk2(b.z, b.w);
        if (m == 2) {
            *(uint2*)&Lt[i * 32 + tr][d8 * 8]     = make_uint2(p0, p1);
            *(uint2*)&Lt[i * 32 + tr][d8 * 8 + 4] = make_uint2(p2, p3);
        } else if (t < T) {
            unsigned short* dst = Kb + ((size_t)h * T + t) * DH + d8 * 8;
            *(uint4*)dst = make_uint4(p0, p1, p2, p3);
        }
    }
    if (m == 2) {
        __syncthreads();
        const int d = tid >> 2, tg = tid & 3;
        #pragma unroll
        for (int p = 0; p < 2; ++p) {
            int G = tg + 4 * p;
            int td = t0 + G * 8;
            unsigned u[4];
            #pragma unroll
            for (int jj = 0; jj < 4; ++jj)
                u[jj] = (unsigned)Lt[G * 8 + 2 * jj][d] |
                        ((unsigned)Lt[G * 8 + 2 * jj + 1][d] << 16);
            if (td < T)
                *(uint4*)(Vtb + ((size_t)h * DH + d) * T + td) =
                    make_uint4(u[0], u[1], u[2], u[3]);
        }
    }
}

// ---------------- main flash kernel ----------------
__global__ __launch_bounds__(256, 2)
void fa_main(const float* __restrict__ qkv, const unsigned short* __restrict__ Kb,
             const unsigned short* __restrict__ Vtb, const int* __restrict__ cu,
             int n_cu, int T, float* __restrict__ out) {
    // Double-buffered staging tiles. Four DISTINCT shared objects so alias
    // analysis can prove the DMA writes (next buf) don't touch the ds_reads (cur buf).
    __shared__ unsigned short Ksh0[TK * DH];   // swizzled 16B granules: g = row*8 + (gd^(row&7))
    __shared__ unsigned short Ksh1[TK * DH];
    __shared__ unsigned short Vsh0[DH * TK];   // same swizzle, rows = d, cols = keys
    __shared__ unsigned short Vsh1[DH * TK];
    __shared__ unsigned short Psh[TQ][PSTR];

    const int tid = threadIdx.x;
    const int h = blockIdx.y, t0 = blockIdx.x * TQ;
    const int w = tid >> 6, lane = tid & 63, n15 = lane & 15, quad = lane >> 4;

    // ---- segment bounds ----
    int trow = t0 + w * 16 + n15; if (trow > T - 1) trow = T - 1;
    int lo, hi;
    { int s = 0; for (int j = 1; j < n_cu - 1; ++j) if (cu[j] <= trow) s = j;
      lo = cu[s]; hi = cu[s + 1]; }
    int kb_, ke;
    { int s = 0; for (int j = 1; j < n_cu - 1; ++j) if (cu[j] <= t0) s = j;
      kb_ = cu[s];
      int tl = t0 + TQ - 1; if (tl > T - 1) tl = T - 1;
      s = 0; for (int j = 1; j < n_cu - 1; ++j) if (cu[j] <= tl) s = j;
      ke = cu[s + 1]; }

    // ---- Q fragments: load fp32, scale by D^-0.5, pack bf16 in-register ----
    s16x8 qfrag[2];
    {
        int tc = t0 + w * 16 + n15; if (tc > T - 1) tc = T - 1;
        const float* qp = qkv + (size_t)tc * 3 * (HEADS * DH) + h * DH;
        #pragma unroll
        for (int f = 0; f < 2; ++f) {
            const float* p = qp + f * 32 + quad * 8;
            float4 a = *(const float4*)p;
            float4 b = *(const float4*)(p + 4);
            union { unsigned u[4]; s16x8 v; } cv;
            cv.u[0] = pk2(a.x * 0.125f, a.y * 0.125f);
            cv.u[1] = pk2(a.z * 0.125f, a.w * 0.125f);
            cv.u[2] = pk2(b.x * 0.125f, b.y * 0.125f);
            cv.u[3] = pk2(b.z * 0.125f, b.w * 0.125f);
            qfrag[f] = cv.v;
        }
    }

    // ---- staging lane constants ----
    const unsigned short* kb_h = Kb + (size_t)h * T * DH;
    const unsigned short* vt_h = Vtb + (size_t)h * DH * T;
    int krow_rel[2], vkey_off[2];
    const unsigned short* kbase[2];
    const unsigned short* vbase[2];
    #pragma unroll
    for (int i = 0; i < 2; ++i) {
        int gg = i * 64 + lane;           // wave-local granule 0..127
        int rr = gg >> 3;                 // 0..15
        int gc = gg & 7;
        int row = w * 16 + rr;            // K row / V d-row (0..63)
        int gcol = gc ^ (row & 7);
        krow_rel[i] = row;
        kbase[i] = kb_h + gcol * 8;                 // + rk*64 per chunk
        vbase[i] = vt_h + (size_t)row * T;          // + key per chunk
        vkey_off[i] = gcol * 8;
    }
    // fragment read byte-offsets (valid for both K and V tiles)
    int off16[2];
    #pragma unroll
    for (int kh = 0; kh < 2; ++kh)
        off16[kh] = n15 * 128 + (((kh * 4 + quad) ^ (n15 & 7)) * 16);

    f32x4 oacc[4];
    #pragma unroll
    for (int i = 0; i < 4; ++i) oacc[i] = (f32x4){0.f, 0.f, 0.f, 0.f};
    float m_ = NEG_BIG, l_ = 0.f;

    auto STAGE = [&](unsigned short* Kd, unsigned short* Vd, int c0s) {
        #pragma unroll
        for (int i = 0; i < 2; ++i) {
            int rk = c0s + krow_rel[i]; if (rk > T - 1) rk = T - 1;
            __builtin_amdgcn_global_load_lds(
                (const __attribute__((address_space(1))) void*)(kbase[i] + ((size_t)rk << 6)),
                (__attribute__((address_space(3))) void*)&Kd[(w * 128 + i * 64) * 8],
                16, 0, 0);
            int kv = c0s + vkey_off[i]; if (kv > T - 8) kv = T - 8;
            __builtin_amdgcn_global_load_lds(
                (const __attribute__((address_space(1))) void*)(vbase[i] + kv),
                (__attribute__((address_space(3))) void*)&Vd[(w * 128 + i * 64) * 8],
                16, 0, 0);
        }
    };

    auto COMPUTE = [&](const unsigned short* Ks, const unsigned short* Vs, int c0) {
        // ---- S^T = K·Q^T : lane holds S[q=n15][key = nt*16 + quad*4 + reg] ----
        const char* Kc = (const char*)Ks;
        f32x4 sacc[4];
        __builtin_amdgcn_s_setprio(1);
        #pragma unroll
        for (int nt = 0; nt < 4; ++nt) {
            s16x8 k0 = *(const s16x8*)(Kc + nt * 2048 + off16[0]);
            s16x8 k1 = *(const s16x8*)(Kc + nt * 2048 + off16[1]);
            f32x4 z = (f32x4){0.f, 0.f, 0.f, 0.f};
            z = __builtin_amdgcn_mfma_f32_16x16x32_bf16(k0, qfrag[0], z, 0, 0, 0);
            z = __builtin_amdgcn_mfma_f32_16x16x32_bf16(k1, qfrag[1], z, 0, 0, 0);
            sacc[nt] = z;
        }
        __builtin_amdgcn_s_setprio(0);

        // ---- mask (only for boundary chunks; never taken when tiles align) ----
        if (!(c0 >= lo && c0 + TK <= hi)) {
            #pragma unroll
            for (int nt = 0; nt < 4; ++nt)
                #pragma unroll
                for (int reg = 0; reg < 4; ++reg) {
                    int key = c0 + nt * 16 + quad * 4 + reg;
                    bool valid = (key >= lo) && (key < hi);
                    sacc[nt][reg] = valid ? sacc[nt][reg] : NEG_BIG;
                }
        }

        // ---- online softmax (row = n15; reduce across quad lanes) ----
        float rm = NEG_BIG;
        #pragma unroll
        for (int nt = 0; nt < 4; ++nt)
            #pragma unroll
            for (int reg = 0; reg < 4; ++reg) rm = fmaxf(rm, sacc[nt][reg]);
        rm = fmaxf(rm, __shfl_xor(rm, 16));
        rm = fmaxf(rm, __shfl_xor(rm, 32));

        // defer-max (exact with THR=0: if no row's max grew, alpha == 1)
        if (__any(rm > m_)) {
            float mn = fmaxf(m_, rm);
            float alpha = exp2f((m_ - mn) * L2E);
            l_ *= alpha;
            m_ = mn;
            #pragma unroll
            for (int reg = 0; reg < 4; ++reg) {
                float ar = __shfl(alpha, quad * 4 + reg);
                oacc[0][reg] *= ar; oacc[1][reg] *= ar;
                oacc[2][reg] *= ar; oacc[3][reg] *= ar;
            }
        }
        float mnl = m_ * L2E;
        float rs = 0.f;
        #pragma unroll
        for (int nt = 0; nt < 4; ++nt) {
            float p0 = exp2f(fmaf(sacc[nt][0], L2E, -mnl));
            float p1 = exp2f(fmaf(sacc[nt][1], L2E, -mnl));
            float p2 = exp2f(fmaf(sacc[nt][2], L2E, -mnl));
            float p3 = exp2f(fmaf(sacc[nt][3], L2E, -mnl));
            rs += (p0 + p1) + (p2 + p3);
            *(uint2*)&Psh[w * 16 + n15][nt * 16 + quad * 4] =
                make_uint2(pk2(p0, p1), pk2(p2, p3));
        }
        rs += __shfl_xor(rs, 16);
        rs += __shfl_xor(rs, 32);
        l_ += rs;

        // ---- PV: O += P·V ----
        s16x8 afr[2];
        afr[0] = *(const s16x8*)&Psh[w * 16 + n15][quad * 8];
        afr[1] = *(const s16x8*)&Psh[w * 16 + n15][32 + quad * 8];
        const char* Vc = (const char*)Vs;
        __builtin_amdgcn_s_setprio(1);
        #pragma unroll
        for (int nt = 0; nt < 4; ++nt) {
            s16x8 v0 = *(const s16x8*)(Vc + nt * 2048 + off16[0]);
            s16x8 v1 = *(const s16x8*)(Vc + nt * 2048 + off16[1]);
            oacc[nt] = __builtin_amdgcn_mfma_f32_16x16x32_bf16(afr[0], v0, oacc[nt], 0, 0, 0);
            oacc[nt] = __builtin_amdgcn_mfma_f32_16x16x32_bf16(afr[1], v1, oacc[nt], 0, 0, 0);
        }
        __builtin_amdgcn_s_setprio(0);
    };

    // ---- double-buffered main loop: 1 barrier per chunk, DMA hidden under compute ----
    const int nIter = (ke - kb_) / TK;
    int c0 = kb_;
    int rem = nIter;

    STAGE(Ksh0, Vsh0, c0);
    __syncthreads();                       // vmcnt(0) drain + barrier: buf0 ready

    for (;;) {
        if (rem > 1) STAGE(Ksh1, Vsh1, c0 + TK);
        COMPUTE(Ksh0, Vsh0, c0);
        __syncthreads();                   // drains this iter's STAGE; buf1 ready
        if (--rem == 0) break;
        c0 += TK;

        if (rem > 1) STAGE(Ksh0, Vsh0, c0 + TK);
        COMPUTE(Ksh1, Vsh1, c0);
        __syncthreads();
        if (--rem == 0) break;
        c0 += TK;
    }

    // ---- epilogue: normalize + direct store ----
    #pragma unroll
    for (int reg = 0; reg < 4; ++reg) {
        float lr = __shfl(l_, quad * 4 + reg);
        float inv = 1.f / fmaxf(lr, 1e-30f);
        int t = t0 + w * 16 + quad * 4 + reg;
        if (t < T) {
            #pragma unroll
            for (int nt = 0; nt < 4; ++nt)
                out[((size_t)t * HEADS + h) * DH + nt * 16 + n15] = oacc[nt][reg] * inv;
        }
    }
}

extern "C" void kernel_launch(void* const* d_in, const int* in_sizes, int n_in,
                              void* d_out, int out_size, void* d_ws, size_t ws_size,
                              hipStream_t stream) {
    const float* qkv = (const float*)d_in[0];
    const int* cu    = (const int*)d_in[1];
    const int n_cu   = in_sizes[1];
    const int T      = in_sizes[0] / (3 * HEADS * DH);
    float* out       = (float*)d_out;

    size_t elems = (size_t)T * HEADS * DH;
    unsigned short* Kb  = (unsigned short*)d_ws;   // elems bf16
    unsigned short* Vtb = Kb + elems;              // elems bf16

    int tiles = (T + TQ - 1) / TQ;
    dim3 pgrid(tiles, HEADS, 2);
    prep_kernel<<<pgrid, 256, 0, stream>>>(qkv, Kb, Vtb, T);

    dim3 grid(tiles, HEADS);
    fa_main<<<grid, 256, 0, stream>>>(qkv, Kb, Vtb, cu, n_cu, T, out);
}